// Round 1
// baseline (277.231 us; speedup 1.0000x reference)
//
#include <hip/hip_runtime.h>
#include <math.h>

// BundleAdjustmentModel: project N 3D points into V=64 camera views.
// out[v][n] = (u,v), u = -f*X/safe_z + cx, v = f*Y/safe_z + cy,
// [X,Y,Z] = R_v * p_n + t_v, R_v = Rx*Ry*Rz (euler xyz), t_v = (tx,ty,-(softplus(d)+0.25))
//
// Memory-bound: writes 256 MB, reads 6 MB. Demonstrated write ceiling (harness
// fill kernel) is ~6.6 TB/s; previous version ran at ~2.5 TB/s because only
// 3908 waves each ran a 64-view serial dependent chain (MLP-starved).
//
// This version:
//  - grid.y=4: each block handles VT=16 views -> 4x waves, 4x shorter chains.
//    (points re-read 4x = 24 MB, negligible vs 256 MB writes)
//  - each thread owns 2 CONSECUTIVE points -> one float4 store per view
//    (16 B/lane coalescing sweet spot, half the store instructions).
//    Alignment: (v*N + n0)*8 with n0 even and N*8 % 16 == 0 -> 16B aligned.
//  - focal folded into the per-view LDS rows: row0' = -f*R0 (u), row1' = +f*R1 (v),
//    row2 unscaled (z). Inner loop: 9 FMA + sign/max/mul + rcp + 2 FMA per point.

#define NVIEW 64
#define VT 16            // views per block; grid.y = NVIEW/VT
#define BLOCK 256
#define Z_EPS 1e-4f

__device__ __forceinline__ float softplus_f(float x) {
    // stable: max(x,0) + log1p(exp(-|x|))
    return fmaxf(x, 0.0f) + log1pf(expf(-fabsf(x)));
}

__global__ __launch_bounds__(BLOCK) void ba_project_kernel(
    const float* __restrict__ points,          // (N,3)
    const float* __restrict__ euler,           // (V,3)
    const float* __restrict__ txy,             // (V,2)
    const float* __restrict__ tdr,             // (V,)
    const float* __restrict__ focal_raw,       // (1,)
    const int*   __restrict__ cxp,             // (1,)
    const int*   __restrict__ cyp,             // (1,)
    float2* __restrict__ out,                  // (V,N) float2
    int N)
{
    // Per-view constants for this block's VT views: rows [-f*R0|-f*tx],
    // [f*R1|f*ty], [R2|tz] packed as 3 float4s per view.
    __shared__ float4 vd[VT * 3];

    const int tid = threadIdx.x;
    const float focal = softplus_f(focal_raw[0]) + 50.0f;

    if (tid < VT) {
        const int v = blockIdx.y * VT + tid;
        float ex = euler[v * 3 + 0];
        float ey = euler[v * 3 + 1];
        float ez = euler[v * 3 + 2];
        float sx, cx_, sy, cy_, sz, cz;
        sincosf(ex, &sx, &cx_);
        sincosf(ey, &sy, &cy_);
        sincosf(ez, &sz, &cz);
        // R = Rx @ Ry @ Rz
        float r00 = cy_ * cz;
        float r01 = -cy_ * sz;
        float r02 = sy;
        float r10 = cx_ * sz + sx * sy * cz;
        float r11 = cx_ * cz - sx * sy * sz;
        float r12 = -sx * cy_;
        float r20 = sx * sz - cx_ * sy * cz;
        float r21 = sx * cz + cx_ * sy * sz;
        float r22 = cx_ * cy_;

        float tx = txy[v * 2 + 0];
        float ty = txy[v * 2 + 1];
        float tz = -(softplus_f(tdr[v]) + 0.25f);

        vd[tid * 3 + 0] = make_float4(-focal * r00, -focal * r01, -focal * r02, -focal * tx);
        vd[tid * 3 + 1] = make_float4( focal * r10,  focal * r11,  focal * r12,  focal * ty);
        vd[tid * 3 + 2] = make_float4(r20, r21, r22, tz);
    }
    __syncthreads();

    const float ccx = (float)cxp[0];
    const float ccy = (float)cyp[0];

    // Each thread owns the consecutive point pair {2*pair, 2*pair+1}.
    const int pair = blockIdx.x * BLOCK + tid;
    const int n0 = pair * 2;
    if (n0 >= N) return;
    const bool full = (n0 + 1 < N);   // N=500000 is even; guard stays general

    // 6 floats of the pair: (x0,y0),(z0,x1),(y1,z1) as float2s (8B aligned).
    const float2* p2 = (const float2*)points;
    float2 a = p2[pair * 3 + 0];
    float2 b, c;
    if (full) {
        b = p2[pair * 3 + 1];
        c = p2[pair * 3 + 2];
    } else {
        b = make_float2(points[(size_t)n0 * 3 + 2], 0.0f);  // z0 only, no OOB read
        c = make_float2(0.0f, 0.0f);
    }
    const float x0 = a.x, y0 = a.y, z0 = b.x;
    const float x1 = b.y, y1 = c.x, z1 = c.y;

    float2* outp = out + (size_t)(blockIdx.y * VT) * N + n0;

#pragma unroll 2
    for (int v = 0; v < VT; ++v) {
        float4 A = vd[v * 3 + 0];   // broadcast ds_read_b128, conflict-free
        float4 B = vd[v * 3 + 1];
        float4 C = vd[v * 3 + 2];

        // point 0
        float X0 = fmaf(A.x, x0, fmaf(A.y, y0, fmaf(A.z, z0, A.w)));
        float Y0 = fmaf(B.x, x0, fmaf(B.y, y0, fmaf(B.z, z0, B.w)));
        float Z0 = fmaf(C.x, x0, fmaf(C.y, y0, fmaf(C.z, z0, C.w)));
        float sg0  = (Z0 >= 0.0f) ? 1.0f : -1.0f;
        float t0   = __builtin_amdgcn_rcpf(sg0 * fmaxf(fabsf(Z0), Z_EPS));
        float u0 = fmaf(X0, t0, ccx);
        float w0 = fmaf(Y0, t0, ccy);

        // point 1
        float X1 = fmaf(A.x, x1, fmaf(A.y, y1, fmaf(A.z, z1, A.w)));
        float Y1 = fmaf(B.x, x1, fmaf(B.y, y1, fmaf(B.z, z1, B.w)));
        float Z1 = fmaf(C.x, x1, fmaf(C.y, y1, fmaf(C.z, z1, C.w)));
        float sg1  = (Z1 >= 0.0f) ? 1.0f : -1.0f;
        float t1   = __builtin_amdgcn_rcpf(sg1 * fmaxf(fabsf(Z1), Z_EPS));
        float u1 = fmaf(X1, t1, ccx);
        float w1 = fmaf(Y1, t1, ccy);

        if (full) {
            *(float4*)outp = make_float4(u0, w0, u1, w1);  // 16B coalesced store
        } else {
            *outp = make_float2(u0, w0);
        }
        outp += N;
    }
}

extern "C" void kernel_launch(void* const* d_in, const int* in_sizes, int n_in,
                              void* d_out, int out_size, void* d_ws, size_t ws_size,
                              hipStream_t stream) {
    const float* points    = (const float*)d_in[0];
    const float* euler     = (const float*)d_in[1];
    const float* txy       = (const float*)d_in[2];
    const float* tdr       = (const float*)d_in[3];
    const float* focal_raw = (const float*)d_in[4];
    const int*   cxp       = (const int*)d_in[5];
    const int*   cyp       = (const int*)d_in[6];

    const int N = in_sizes[0] / 3;
    const int pairs = (N + 1) / 2;
    dim3 grid((pairs + BLOCK - 1) / BLOCK, NVIEW / VT, 1);

    ba_project_kernel<<<grid, dim3(BLOCK, 1, 1), 0, stream>>>(
        points, euler, txy, tdr, focal_raw, cxp, cyp, (float2*)d_out, N);
}